// Round 1
// baseline (201.127 us; speedup 1.0000x reference)
//
#include <hip/hip_runtime.h>

// CTC forward loss, B=512, T=512 (Tp=510 after [:,2:,:]), C=96, L=64, S=129.
// One wave per batch element; DP states live in registers (lane l holds
// states 2l, 2l+1; lane 63 additionally state 128). Base-2 log space
// (native v_exp_f32 / v_log_f32); per-step log-softmax normalizer is
// accumulated separately (logaddexp shift-invariance) and folded in at the end.

constexpr int   T_   = 512;
constexpr int   C_   = 96;
constexpr int   L_   = 64;
constexpr int   TP_  = 510;          // T - 2
constexpr float EPS_ = 1e-7f;
constexpr float NEG_ = -1e30f;
constexpr float LN2_ = 0.69314718055994530942f;

#if __has_builtin(__builtin_amdgcn_logf)
__device__ __forceinline__ float flog2(float x) { return __builtin_amdgcn_logf(x); }
#else
__device__ __forceinline__ float flog2(float x) { return log2f(x); }
#endif
#if __has_builtin(__builtin_amdgcn_exp2f)
__device__ __forceinline__ float fexp2(float x) { return __builtin_amdgcn_exp2f(x); }
#else
__device__ __forceinline__ float fexp2(float x) { return exp2f(x); }
#endif

// logaddexp in base-2: log2(2^x + 2^y)
__device__ __forceinline__ float lae2(float x, float y) {
  float m = fmaxf(x, y);
  return m + flog2(fexp2(x - m) + fexp2(y - m));
}
__device__ __forceinline__ float lae3(float x, float y, float z) {
  float m = fmaxf(fmaxf(x, y), z);
  return m + flog2(fexp2(x - m) + fexp2(y - m) + fexp2(z - m));
}

__global__ __launch_bounds__(64, 1) void ctc_fwd(
    const int* __restrict__ y_true, const float* __restrict__ y_pred,
    const int* __restrict__ input_len, const int* __restrict__ label_len,
    float* __restrict__ out)
{
  const int b = blockIdx.x;
  const int l = threadIdx.x;   // 0..63

  // row pointer: skip first two time steps ([:, 2:, :])
  const float2* __restrict__ rp =
      reinterpret_cast<const float2*>(y_pred + (size_t)b * T_ * C_ + 2 * C_);
  const bool ld = (l < 48);    // 48 lanes x float2 = 96 floats per row

  const int  lab     = y_true[b * L_ + l];       // label for odd state 2l+1
  const int  labPrev = __shfl_up(lab, 1);
  const bool skipOK  = (l >= 1) && (lab != labPrev);
  const int  ilen    = input_len[b];
  const int  llen    = label_len[b];
  const int  tmax    = ilen < TP_ ? ilen : TP_;

  auto loadRow = [&](int t) -> float2 {
    int tc = t < TP_ ? t : TP_ - 1;   // clamp (over-prefetch tail)
    float2 r = make_float2(0.f, 0.f);
    if (ld) r = rp[(size_t)tc * 48 + l];
    return r;
  };

  // prefetch ring, depth 4 (static indices only)
  float2 p0 = loadRow(0), p1 = loadRow(1), p2 = loadRow(2), p3 = loadRow(3);

  float aE, aO, aX = NEG_;   // alpha[2l], alpha[2l+1], alpha[128] (lane 63)
  float lseAcc;              // sum over active t of log2(sum_c(p+EPS))

  { // t = 0: alpha0 = lp_ext[0] for s<2 else NEG
    float2 v = p0;
    float s = ld ? (v.x + v.y) : 0.f;
    s += __shfl_xor(s, 1);  s += __shfl_xor(s, 2);  s += __shfl_xor(s, 4);
    s += __shfl_xor(s, 8);  s += __shfl_xor(s, 16); s += __shfl_xor(s, 32);
    float sum = s + C_ * EPS_;
    float lx = flog2(v.x + EPS_), ly = flog2(v.y + EPS_);
    float gx = __shfl(lx, lab >> 1), gy = __shfl(ly, lab >> 1);
    float lpL = (lab & 1) ? gy : gx;
    float lpB = __shfl(ly, 47);             // column 95 = BLANK
    lseAcc = flog2(sum);
    aE = (l == 0) ? lpB : NEG_;
    aO = (l == 0) ? lpL : NEG_;
  }
  p0 = loadRow(4);

  auto step = [&](int t, float2 v) {
    if (t >= tmax) return;                  // uniform per block
    float s = ld ? (v.x + v.y) : 0.f;
    s += __shfl_xor(s, 1);  s += __shfl_xor(s, 2);  s += __shfl_xor(s, 4);
    s += __shfl_xor(s, 8);  s += __shfl_xor(s, 16); s += __shfl_xor(s, 32);
    float sum = s + C_ * EPS_;
    float lx = flog2(v.x + EPS_), ly = flog2(v.y + EPS_);
    float gx = __shfl(lx, lab >> 1), gy = __shfl(ly, lab >> 1);
    float lpL = (lab & 1) ? gy : gx;        // lp2 at labels[l]  (state 2l+1)
    float lpB = __shfl(ly, 47);             // lp2 at BLANK      (even states)
    float a1 = __shfl_up(aO, 1);            // alpha[2l-1]
    if (l == 0) a1 = NEG_;
    // even state 2l (blank, never skips): alpha[2l], alpha[2l-1]
    float nE = lae2(aE, a1) + lpB;
    // odd state 2l+1: alpha[2l+1], alpha[2l], (skip) alpha[2l-1]
    float nO = lae3(aO, aE, skipOK ? a1 : NEG_) + lpL;
    // state 128 (blank): alpha[128], alpha[127] — lane 63 only
    if (l == 63) aX = lae2(aX, aO) + lpB;
    aE = nE; aO = nO;
    lseAcc += flog2(sum);
  };

  // t = 1..512 (t >= tmax masked off); keep outer loop rolled — the 4-step
  // body provides static ring indices and prefetch distance 4.
#pragma unroll 1
  for (int tb = 1; tb <= 509; tb += 4) {
    step(tb + 0, p1); p1 = loadRow(tb + 4);
    step(tb + 1, p2); p2 = loadRow(tb + 5);
    step(tb + 2, p3); p3 = loadRow(tb + 6);
    step(tb + 3, p0); p0 = loadRow(tb + 7);
  }

  // s_last = 2*llen in [32,128]; a_last = alpha[s_last], a_prev = alpha[s_last-1]
  float aL = (llen >= 64) ? __shfl(aX, 63) : __shfl(aE, llen);
  float aP = __shfl(aO, llen - 1);
  if (l == 0) out[b] = -LN2_ * (lae2(aL, aP) - lseAcc);
}

extern "C" void kernel_launch(void* const* d_in, const int* in_sizes, int n_in,
                              void* d_out, int out_size, void* d_ws, size_t ws_size,
                              hipStream_t stream) {
  const int*   y_true = (const int*)d_in[0];
  const float* y_pred = (const float*)d_in[1];
  const int*   ilen   = (const int*)d_in[2];
  const int*   llen   = (const int*)d_in[3];
  float*       out    = (float*)d_out;
  const int    B      = out_size;   // 512
  hipLaunchKernelGGL(ctc_fwd, dim3(B), dim3(64), 0, stream,
                     y_true, y_pred, ilen, llen, out);
}

// Round 3
// 46.055 us; speedup vs baseline: 4.3671x; 4.3671x over previous
//
#include <hip/hip_runtime.h>

// CTC forward loss, B=512, T=512 (Tp=510 after [:,2:,:]), C=96, L=64, S=129.
// One wave per batch element. Log2-space DP (validated in round 1, absmax 0.0):
// lane l holds states 2l, 2l+1 (lane 63 also state 128 when llen==64).
//  - normalizer: sum_c(p+EPS) == 1 + C*EPS exactly (p is softmax output), so
//    log-softmax correction is the constant tmax*log2(1+C*EPS) — no row reads.
//  - p[t][label] / p[t][blank] gathered straight from global, prefetched
//    32 steps ahead in static register rings (all indices compile-time).
//  - cross-lane alpha[2l-1] via DPP wave_shr1 (old=NEG, bound_ctrl=false);
//    no LDS on the DP chain at all.
//  - lae2(x,y) = m + log2(1 + 2^-|x-y|)  (1 exp + 1 log);
//    nO folds through u = lae2(aE, a1) when skip is allowed.

constexpr int   T_    = 512;
constexpr int   C_    = 96;
constexpr int   L_    = 64;
constexpr int   TP_   = 510;          // T - 2
constexpr float EPS_  = 1e-7f;
constexpr float NEG_  = -1e30f;
constexpr float LN2_  = 0.69314718055994530942f;
constexpr float LSE1_ = 1.3849806e-5f;   // log2(1 + C_*EPS_)

__device__ __forceinline__ float flog2(float x) {
#if __has_builtin(__builtin_amdgcn_logf)
  return __builtin_amdgcn_logf(x);
#else
  return log2f(x);
#endif
}
__device__ __forceinline__ float fexp2(float x) {
#if __has_builtin(__builtin_amdgcn_exp2f)
  return __builtin_amdgcn_exp2f(x);
#else
  return exp2f(x);
#endif
}

template<int CTRL, int RM, int BM, bool BC>
__device__ __forceinline__ float dppf(float old_, float src) {
  return __int_as_float(__builtin_amdgcn_update_dpp(
      __float_as_int(old_), __float_as_int(src), CTRL, RM, BM, BC));
}

// log2(2^x + 2^y); exact for NEG inputs (exp2(-huge) -> 0).
__device__ __forceinline__ float lae2(float x, float y) {
  float m = fmaxf(x, y);
  return m + flog2(1.f + fexp2(-fabsf(x - y)));
}

__global__ __launch_bounds__(64, 1) void ctc_fwd(
    const int* __restrict__ y_true, const float* __restrict__ y_pred,
    const int* __restrict__ input_len, const int* __restrict__ label_len,
    float* __restrict__ out)
{
  const int b = blockIdx.x;
  const int l = threadIdx.x;   // 0..63

  const float* __restrict__ rp = y_pred + (size_t)b * T_ * C_ + 2 * C_;
  const int  lab     = y_true[b * L_ + l];        // label of odd state 2l+1
  const int  labPrev = __shfl_up(lab, 1);
  const bool skipOK  = (l >= 1) && (lab != labPrev);
  const int  ilen    = input_len[b];
  const int  llen    = label_len[b];               // in [16, 64]
  const int  tmax    = ilen < TP_ ? ilen : TP_;

  auto loadPL = [&](int t) -> float {
    int tc = t < TP_ ? t : TP_ - 1;
    return rp[(size_t)tc * C_ + lab];
  };
  auto loadPB = [&](int t) -> float {
    int tc = t < TP_ ? t : TP_ - 1;
    return rp[(size_t)tc * C_ + (C_ - 1)];
  };

  float aE, aO, aX = NEG_;   // log2 alpha[2l], alpha[2l+1], alpha[128]
  { // t = 0: alpha0 = lp for s < 2, else NEG
    float lpb0 = flog2(loadPB(0) + EPS_);
    float lpl0 = flog2(loadPL(0) + EPS_);
    aE = (l == 0) ? lpb0 : NEG_;
    aO = (l == 0) ? lpl0 : NEG_;
  }

  // prefetch rings: 4 groups x 8 steps = 32 steps ahead (static indices only)
  float plr[4][8], pbr[4][8];
#pragma unroll
  for (int g = 0; g < 4; ++g)
#pragma unroll
    for (int j = 0; j < 8; ++j) {
      plr[g][j] = loadPL(1 + g * 8 + j);
      pbr[g][j] = loadPB(1 + g * 8 + j);
    }

  int tbEnd = 1;   // first t not covered by the fast loop

  auto runDP = [&](auto has128) {
    auto stepU = [&](float pl, float pb) {
      float lpl = flog2(pl + EPS_);
      float lpb = flog2(pb + EPS_);
      float a1  = dppf<0x138, 0xf, 0xf, false>(NEG_, aO);  // wave_shr1: aO[l-1]
      float u   = lae2(aE, a1);                 // log2(2^aE + 2^a1)
      float nE  = u + lpb;                      // even state 2l
      float v   = skipOK ? u : aE;              // fold skip term through u
      float nO  = lae2(aO, v) + lpl;            // odd state 2l+1
      if constexpr (decltype(has128)::value)
        aX = lae2(aX, aO) + lpb;                // state 128 (lane 63 slot)
      aE = nE; aO = nO;
    };

    int tb = 1;
#pragma unroll 1
    for (; tb + 32 <= tmax; tb += 32) {
#pragma unroll
      for (int g = 0; g < 4; ++g) {
#pragma unroll
        for (int j = 0; j < 8; ++j) stepU(plr[g][j], pbr[g][j]);
#pragma unroll
        for (int j = 0; j < 8; ++j) {
          int t2 = tb + 32 + g * 8 + j;
          plr[g][j] = loadPL(t2);
          pbr[g][j] = loadPB(t2);
        }
      }
    }
    // guarded tail: rings hold t = tb .. tb+31 (clamped loads, steps guarded)
#pragma unroll
    for (int g = 0; g < 4; ++g)
#pragma unroll
      for (int j = 0; j < 8; ++j) {
        int t = tb + g * 8 + j;
        if (t < tmax) stepU(plr[g][j], pbr[g][j]);
      }
    tbEnd = tb;
  };

  if (llen >= 64) runDP(std::integral_constant<bool, true>{});
  else            runDP(std::integral_constant<bool, false>{});

  // s_last = 2*llen in [32,128]
  float aL = (llen >= 64) ? __shfl(aX, 63) : __shfl(aE, llen);
  float aP = __shfl(aO, llen - 1);
  if (l == 0)
    out[b] = -LN2_ * (lae2(aL, aP) - (float)tmax * LSE1_);
}

extern "C" void kernel_launch(void* const* d_in, const int* in_sizes, int n_in,
                              void* d_out, int out_size, void* d_ws, size_t ws_size,
                              hipStream_t stream) {
  const int*   y_true = (const int*)d_in[0];
  const float* y_pred = (const float*)d_in[1];
  const int*   ilen   = (const int*)d_in[2];
  const int*   llen   = (const int*)d_in[3];
  float*       outp   = (float*)d_out;
  const int    B      = out_size;   // 512
  hipLaunchKernelGGL(ctc_fwd, dim3(B), dim3(64), 0, stream,
                     y_true, y_pred, ilen, llen, outp);
}

// Round 4
// 41.239 us; speedup vs baseline: 4.8771x; 1.1168x over previous
//
#include <hip/hip_runtime.h>

// CTC forward loss, B=512, T=512 (Tp=510 after [:,2:,:]), C=96, L=64, S=129.
// One wave per batch element. DP in PER-LANE scaled linear space:
// lane l holds states 2l, 2l+1 (lane 63 also state 128 when llen==64) as
// mantissas mE, mO (,mX) with a shared per-lane int exponent e:
//   true alpha = m * 2^e.
// Per step (all full-rate VALU, zero transcendentals on the chain):
//   - neighbor (mO, e) via DPP wave_shr1; align a1 = ldexp(m1, e1-e)
//   - nE = (mE + a1)*pb ; nO = (mO + mE + skip*a1)*pl ; nX = (mX + mO)*pb
//   - renorm: k = biased_exp(lane max) via bit shift; e += k-127; ldexp the
//     mantissas back to [1,2). Empty lanes adopt the left neighbor's exponent
//     so the arriving wavefront value is representable.
// Per-lane scaling is the fix for round 2's failure: cross-STATE spread
// (~2^170) broke a wave-shared scale, but within-lane spread is ~2^50.
// p[t][label] / p[t][blank] gathered from global, prefetched 32 steps ahead
// in static register rings (validated structure from round 3).
// log-softmax normalizer: sum_c(p+EPS) == 1 + C*EPS exactly -> constant.

constexpr int   T_    = 512;
constexpr int   C_    = 96;
constexpr int   L_    = 64;
constexpr int   TP_   = 510;          // T - 2
constexpr float EPS_  = 1e-7f;
constexpr float LN2_  = 0.69314718055994530942f;
constexpr float LSE1_ = 1.3849806e-5f;   // log2(1 + C_*EPS_)

__device__ __forceinline__ float flog2(float x) {
#if __has_builtin(__builtin_amdgcn_logf)
  return __builtin_amdgcn_logf(x);
#else
  return log2f(x);
#endif
}
__device__ __forceinline__ float fexp2(float x) {
#if __has_builtin(__builtin_amdgcn_exp2f)
  return __builtin_amdgcn_exp2f(x);
#else
  return exp2f(x);
#endif
}
__device__ __forceinline__ float fldexp(float x, int n) {
#if __has_builtin(__builtin_amdgcn_ldexpf)
  return __builtin_amdgcn_ldexpf(x, n);
#else
  return __builtin_ldexpf(x, n);   // lowers to v_ldexp_f32 on amdgcn
#endif
}

template<int CTRL, int RM, int BM, bool BC>
__device__ __forceinline__ float dppf(float old_, float src) {
  return __int_as_float(__builtin_amdgcn_update_dpp(
      __float_as_int(old_), __float_as_int(src), CTRL, RM, BM, BC));
}
template<int CTRL, int RM, int BM, bool BC>
__device__ __forceinline__ int dppi(int old_, int src) {
  return __builtin_amdgcn_update_dpp(old_, src, CTRL, RM, BM, BC);
}

// log2(2^x + 2^y) — readout only
__device__ __forceinline__ float lae2(float x, float y) {
  float m = fmaxf(x, y);
  return m + flog2(1.f + fexp2(-fabsf(x - y)));
}

__global__ __launch_bounds__(64, 1) void ctc_fwd(
    const int* __restrict__ y_true, const float* __restrict__ y_pred,
    const int* __restrict__ input_len, const int* __restrict__ label_len,
    float* __restrict__ out)
{
  const int b = blockIdx.x;
  const int l = threadIdx.x;   // 0..63

  const float* __restrict__ rp = y_pred + (size_t)b * T_ * C_ + 2 * C_;
  const int  lab     = y_true[b * L_ + l];        // label of odd state 2l+1
  const int  labPrev = __shfl_up(lab, 1);
  const bool skipOK  = (l >= 1) && (lab != labPrev);
  const int  ilen    = input_len[b];
  const int  llen    = label_len[b];               // in [16, 64]
  const int  tmax    = ilen < TP_ ? ilen : TP_;

  const float* __restrict__ colL = rp + lab;       // per-lane column
  const float* __restrict__ colB = rp + (C_ - 1);  // uniform (blank) column

  // per-lane scaled-linear state: alpha = m * 2^e
  float mE, mO, mX = 0.f;
  int   e = 0;

  { // t = 0: alpha0 = p for s < 2, else 0
    mE = (l == 0) ? (colB[0] + EPS_) : 0.f;
    mO = (l == 0) ? (colL[0] + EPS_) : 0.f;
  }

  // prefetch rings: 4 groups x 8 steps = 32 ahead (static indices only)
  float plr[4][8], pbr[4][8];
#pragma unroll
  for (int g = 0; g < 4; ++g)
#pragma unroll
    for (int j = 0; j < 8; ++j) {
      plr[g][j] = colL[(1 + g * 8 + j) * C_];
      pbr[g][j] = colB[(1 + g * 8 + j) * C_];
    }

  auto runDP = [&](auto has128) {
    constexpr bool H128 = decltype(has128)::value;

    auto stepU = [&](float pl, float pb) {
      float plE = pl + EPS_;
      float pbE = pb + EPS_;
      int   e1  = dppi<0x138, 0xf, 0xf, false>(0, e);      // wave_shr1
      float m1  = dppf<0x138, 0xf, 0xf, false>(0.f, mO);   // alpha[2l-1] mant
      int   d   = e1 - e;  d = d < 120 ? d : 120;
      float a1  = fldexp(m1, d);                 // aligned alpha[2l-1]
      float a1s = skipOK ? a1 : 0.f;
      float nE  = (mE + a1) * pbE;               // even state 2l
      float nO  = ((mO + mE) + a1s) * plE;       // odd state 2l+1
      float nX = 0.f, mx;
      if constexpr (H128) { nX = (mX + mO) * pbE; mx = fmaxf(fmaxf(nE, nO), nX); }
      else                { mx = fmaxf(nE, nO); }
      int  kb = __float_as_int(mx) >> 23;        // biased exponent (mx >= 0)
      int  ks = 127 - kb;
      bool z  = (mx == 0.f);
      e  = z ? e1 : (e + kb - 127);              // empty lane adopts neighbor
      mE = fldexp(nE, ks);
      mO = fldexp(nO, ks);
      if constexpr (H128) mX = fldexp(nX, ks);
    };

    int tb = 1;
    // fast loop, unclamped refills: t2 = tb+32 .. tb+63 <= tmax-1 <= 509
#pragma unroll 1
    for (; tb + 64 <= tmax; tb += 32) {
#pragma unroll
      for (int g = 0; g < 4; ++g) {
#pragma unroll
        for (int j = 0; j < 8; ++j) stepU(plr[g][j], pbr[g][j]);
        const float* baseL = colL + (tb + 32 + g * 8) * C_;
        const float* baseB = colB + (tb + 32 + g * 8) * C_;
#pragma unroll
        for (int j = 0; j < 8; ++j) {
          plr[g][j] = baseL[j * C_];
          pbr[g][j] = baseB[j * C_];
        }
      }
    }
    // at most one fast iteration with clamped refills
#pragma unroll 1
    for (; tb + 32 <= tmax; tb += 32) {
#pragma unroll
      for (int g = 0; g < 4; ++g) {
#pragma unroll
        for (int j = 0; j < 8; ++j) stepU(plr[g][j], pbr[g][j]);
#pragma unroll
        for (int j = 0; j < 8; ++j) {
          int t2 = tb + 32 + g * 8 + j;
          int tc = t2 < TP_ ? t2 : TP_ - 1;
          plr[g][j] = colL[tc * C_];
          pbr[g][j] = colB[tc * C_];
        }
      }
    }
    // guarded tail, no refills (rings hold t = tb .. tb+31)
#pragma unroll
    for (int g = 0; g < 4; ++g)
#pragma unroll
      for (int j = 0; j < 8; ++j) {
        int t = tb + g * 8 + j;
        if (t < tmax) stepU(plr[g][j], pbr[g][j]);
      }
  };

  if (llen >= 64) runDP(std::integral_constant<bool, true>{});
  else            runDP(std::integral_constant<bool, false>{});

  // readout: log2(alpha) = log2(m) + e   (transcendentals only here)
  float ef  = (float)e;
  float lgE = flog2(mE) + ef;
  float lgO = flog2(mO) + ef;
  float aL;
  if (llen >= 64) { float lgX = flog2(mX) + ef; aL = __shfl(lgX, 63); }
  else            { aL = __shfl(lgE, llen); }
  float aP = __shfl(lgO, llen - 1);
  if (l == 0)
    out[b] = -LN2_ * (lae2(aL, aP) - (float)tmax * LSE1_);
}

extern "C" void kernel_launch(void* const* d_in, const int* in_sizes, int n_in,
                              void* d_out, int out_size, void* d_ws, size_t ws_size,
                              hipStream_t stream) {
  const int*   y_true = (const int*)d_in[0];
  const float* y_pred = (const float*)d_in[1];
  const int*   ilen   = (const int*)d_in[2];
  const int*   llen   = (const int*)d_in[3];
  float*       outp   = (float*)d_out;
  const int    B      = out_size;   // 512
  hipLaunchKernelGGL(ctc_fwd, dim3(B), dim3(64), 0, stream,
                     y_true, y_pred, ilen, llen, outp);
}

// Round 5
// 35.060 us; speedup vs baseline: 5.7366x; 1.1762x over previous
//
#include <hip/hip_runtime.h>

// CTC forward loss, B=512, T=512 (Tp=510 after [:,2:,:]), C=96, L=64, S=129.
// One wave per batch element. DP in PER-LANE scaled linear space (round-4
// validated): lane l holds states 2l, 2l+1 (lane 63 also state 128 when
// llen==64) as mantissas mE, mO (,mX) with per-lane int exponent e.
// Round-5 changes:
//  - prefetch rings are 8 named ext_vector(8) floats accessed ONLY via
//    literal .s0..s7 (round 3/4: VGPR_Count=20 => ring arrays were in
//    scratch; this forces true registers).
//  - fill phase (t<=64): per-step renorm + empty-lane exponent adoption
//    (wavefront reaches lane l at t~l; round-4 code verbatim).
//    steady phase (all lanes nonzero): renorm every 4 steps; e and the
//    neighbor shift d are constant between renorms -> 11 VALU/step,
//    loop-carried chain ~5 ops. Growth<=3^4 (no overflow); lane max
//    >= 2^-93 between renorms (no denormal at max; bit-shift exponent ok);
//    neighbor exponent gap <= ~95 < clamp 120.
// log-softmax normalizer: sum_c(p+EPS) == 1 + C*EPS exactly -> constant.

constexpr int   T_    = 512;
constexpr int   C_    = 96;
constexpr int   L_    = 64;
constexpr int   TP_   = 510;          // T - 2
constexpr float EPS_  = 1e-7f;
constexpr float LN2_  = 0.69314718055994530942f;
constexpr float LSE1_ = 1.3849806e-5f;   // log2(1 + C_*EPS_)

typedef float f8 __attribute__((ext_vector_type(8)));

__device__ __forceinline__ float flog2(float x) {
#if __has_builtin(__builtin_amdgcn_logf)
  return __builtin_amdgcn_logf(x);
#else
  return log2f(x);
#endif
}
__device__ __forceinline__ float fexp2(float x) {
#if __has_builtin(__builtin_amdgcn_exp2f)
  return __builtin_amdgcn_exp2f(x);
#else
  return exp2f(x);
#endif
}
__device__ __forceinline__ float fldexp(float x, int n) {
#if __has_builtin(__builtin_amdgcn_ldexpf)
  return __builtin_amdgcn_ldexpf(x, n);
#else
  return __builtin_ldexpf(x, n);
#endif
}

template<int CTRL, int RM, int BM, bool BC>
__device__ __forceinline__ float dppf(float old_, float src) {
  return __int_as_float(__builtin_amdgcn_update_dpp(
      __float_as_int(old_), __float_as_int(src), CTRL, RM, BM, BC));
}
template<int CTRL, int RM, int BM, bool BC>
__device__ __forceinline__ int dppi(int old_, int src) {
  return __builtin_amdgcn_update_dpp(old_, src, CTRL, RM, BM, BC);
}

// log2(2^x + 2^y) — readout only
__device__ __forceinline__ float lae2(float x, float y) {
  float m = fmaxf(x, y);
  return m + flog2(1.f + fexp2(-fabsf(x - y)));
}

// ---- ring macros: literal element names only (keep SROA happy) ----
#define LOADG(PL, PB, T0) {                                         \
  const float* _bl = colL + (size_t)(T0) * C_;                      \
  const float* _bb = colB + (size_t)(T0) * C_;                      \
  PL.s0 = _bl[0 * C_]; PB.s0 = _bb[0 * C_];                         \
  PL.s1 = _bl[1 * C_]; PB.s1 = _bb[1 * C_];                         \
  PL.s2 = _bl[2 * C_]; PB.s2 = _bb[2 * C_];                         \
  PL.s3 = _bl[3 * C_]; PB.s3 = _bb[3 * C_];                         \
  PL.s4 = _bl[4 * C_]; PB.s4 = _bb[4 * C_];                         \
  PL.s5 = _bl[5 * C_]; PB.s5 = _bb[5 * C_];                         \
  PL.s6 = _bl[6 * C_]; PB.s6 = _bb[6 * C_]; }                       \
  PL.s7 = *(colL + (size_t)((T0) + 7) * C_); PB.s7 = *(colB + (size_t)((T0) + 7) * C_);

#define LD1C(PL, PB, T0, J) {                                       \
  int _t = (T0) + (J); _t = _t < TP_ ? _t : TP_ - 1;                \
  PL.s##J = colL[(size_t)_t * C_]; PB.s##J = colB[(size_t)_t * C_]; }
#define LOADGC(PL, PB, T0) \
  LD1C(PL,PB,T0,0) LD1C(PL,PB,T0,1) LD1C(PL,PB,T0,2) LD1C(PL,PB,T0,3) \
  LD1C(PL,PB,T0,4) LD1C(PL,PB,T0,5) LD1C(PL,PB,T0,6) LD1C(PL,PB,T0,7)

#define A8(PL, PB) { stepF(PL.s0,PB.s0); stepF(PL.s1,PB.s1);        \
  stepF(PL.s2,PB.s2); stepF(PL.s3,PB.s3); stepF(PL.s4,PB.s4);       \
  stepF(PL.s5,PB.s5); stepF(PL.s6,PB.s6); stepF(PL.s7,PB.s7); }

#define B8(PL, PB) { stepS(PL.s0,PB.s0); stepS(PL.s1,PB.s1);        \
  stepS(PL.s2,PB.s2); stepS(PL.s3,PB.s3); renormS();                \
  stepS(PL.s4,PB.s4); stepS(PL.s5,PB.s5); stepS(PL.s6,PB.s6);       \
  stepS(PL.s7,PB.s7); renormS(); }

#define TAIL1(PL, PB, J, OFF) \
  if ((tb + (OFF) + (J)) < tmax) stepF(PL.s##J, PB.s##J);
#define TAIL8(PL, PB, OFF) \
  TAIL1(PL,PB,0,OFF) TAIL1(PL,PB,1,OFF) TAIL1(PL,PB,2,OFF) TAIL1(PL,PB,3,OFF) \
  TAIL1(PL,PB,4,OFF) TAIL1(PL,PB,5,OFF) TAIL1(PL,PB,6,OFF) TAIL1(PL,PB,7,OFF)

__global__ __launch_bounds__(64, 1) void ctc_fwd(
    const int* __restrict__ y_true, const float* __restrict__ y_pred,
    const int* __restrict__ input_len, const int* __restrict__ label_len,
    float* __restrict__ out)
{
  const int b = blockIdx.x;
  const int l = threadIdx.x;   // 0..63

  const float* __restrict__ rp = y_pred + (size_t)b * T_ * C_ + 2 * C_;
  const int  lab     = y_true[b * L_ + l];        // label of odd state 2l+1
  const int  labPrev = __shfl_up(lab, 1);
  const bool skipOK  = (l >= 1) && (lab != labPrev);
  const int  ilen    = input_len[b];
  const int  llen    = label_len[b];               // in [16, 64]
  const int  tmax    = ilen < TP_ ? ilen : TP_;    // 510 for this data

  const float* __restrict__ colL = rp + lab;       // per-lane column
  const float* __restrict__ colB = rp + (C_ - 1);  // uniform (blank) column

  // per-lane scaled-linear state: alpha = m * 2^e
  float mE, mO, mX = 0.f;
  int   e = 0, d = 0;

  mE = (l == 0) ? (colB[0] + EPS_) : 0.f;
  mO = (l == 0) ? (colL[0] + EPS_) : 0.f;

  f8 pl0, pl1, pl2, pl3, pb0, pb1, pb2, pb3;
  LOADG(pl0, pb0, 1);  LOADG(pl1, pb1, 9);
  LOADG(pl2, pb2, 17); LOADG(pl3, pb3, 25);

  auto runDP = [&](auto has128) {
    constexpr bool H128 = decltype(has128)::value;

    // fill-phase / tail step: per-step renorm + empty-lane adoption (round 4)
    auto stepF = [&](float pl, float pb) {
      float plE = pl + EPS_, pbE = pb + EPS_;
      int   e1  = dppi<0x138, 0xf, 0xf, false>(0, e);
      float m1  = dppf<0x138, 0xf, 0xf, false>(0.f, mO);
      int   dd  = e1 - e;  dd = dd < 120 ? dd : 120;
      float a1  = fldexp(m1, dd);
      float a1s = skipOK ? a1 : 0.f;
      float nE  = (mE + a1) * pbE;
      float nO  = ((mO + mE) + a1s) * plE;
      float nX = 0.f, mx;
      if constexpr (H128) { nX = (mX + mO) * pbE; mx = fmaxf(fmaxf(nE, nO), nX); }
      else                { mx = fmaxf(nE, nO); }
      int  kb = __float_as_int(mx) >> 23;
      int  ks = 127 - kb;
      bool z  = (mx == 0.f);
      e  = z ? e1 : (e + kb - 127);
      mE = fldexp(nE, ks);
      mO = fldexp(nO, ks);
      if constexpr (H128) mX = fldexp(nX, ks);
    };

    // steady step: no renorm; e, d frozen since last renormS
    auto stepS = [&](float pl, float pb) {
      float plE = pl + EPS_, pbE = pb + EPS_;
      float m1  = dppf<0x138, 0xf, 0xf, false>(0.f, mO);
      float a1  = fldexp(m1, d);
      float a1s = skipOK ? a1 : 0.f;
      float nE  = (mE + a1) * pbE;
      float nO  = ((mO + mE) + a1s) * plE;
      if constexpr (H128) mX = (mX + mO) * pbE;
      mE = nE; mO = nO;
    };

    auto renormS = [&]() {
      float mx = fmaxf(mE, mO);
      if constexpr (H128) mx = fmaxf(mx, mX);
      int kb = __float_as_int(mx) >> 23;   // mx > 0, normal (>= 2^-93 rel.)
      int ks = 127 - kb;
      e += kb - 127;
      mE = fldexp(mE, ks);
      mO = fldexp(mO, ks);
      if constexpr (H128) mX = fldexp(mX, ks);
      int e1 = dppi<0x138, 0xf, 0xf, false>(0, e);
      int dd = e1 - e;  d = dd < 120 ? dd : 120;
    };

    int tb = 1;
    // Phase A: robust full blocks until all lanes filled (t > 64)
#pragma unroll 1
    for (; tb < 65 && tb + 64 <= tmax; tb += 32) {
      A8(pl0, pb0); LOADG(pl0, pb0, tb + 32);
      A8(pl1, pb1); LOADG(pl1, pb1, tb + 40);
      A8(pl2, pb2); LOADG(pl2, pb2, tb + 48);
      A8(pl3, pb3); LOADG(pl3, pb3, tb + 56);
    }
    // Phase B: steady, renorm every 4 steps
    renormS();
#pragma unroll 1
    for (; tb + 64 <= tmax; tb += 32) {
      B8(pl0, pb0); LOADG(pl0, pb0, tb + 32);
      B8(pl1, pb1); LOADG(pl1, pb1, tb + 40);
      B8(pl2, pb2); LOADG(pl2, pb2, tb + 48);
      B8(pl3, pb3); LOADG(pl3, pb3, tb + 56);
    }
    // at most one full block with clamped refills (robust steps)
#pragma unroll 1
    for (; tb + 32 <= tmax; tb += 32) {
      A8(pl0, pb0); LOADGC(pl0, pb0, tb + 32);
      A8(pl1, pb1); LOADGC(pl1, pb1, tb + 40);
      A8(pl2, pb2); LOADGC(pl2, pb2, tb + 48);
      A8(pl3, pb3); LOADGC(pl3, pb3, tb + 56);
    }
    // guarded tail: rings hold t = tb .. tb+31
    TAIL8(pl0, pb0, 0); TAIL8(pl1, pb1, 8);
    TAIL8(pl2, pb2, 16); TAIL8(pl3, pb3, 24);
  };

  if (llen >= 64) runDP(std::integral_constant<bool, true>{});
  else            runDP(std::integral_constant<bool, false>{});

  // readout: log2(alpha) = log2(m) + e   (transcendentals only here)
  float ef  = (float)e;
  float lgE = flog2(mE) + ef;
  float lgO = flog2(mO) + ef;
  float aL;
  if (llen >= 64) { float lgX = flog2(mX) + ef; aL = __shfl(lgX, 63); }
  else            { aL = __shfl(lgE, llen); }
  float aP = __shfl(lgO, llen - 1);
  if (l == 0)
    out[b] = -LN2_ * (lae2(aL, aP) - (float)tmax * LSE1_);
}

extern "C" void kernel_launch(void* const* d_in, const int* in_sizes, int n_in,
                              void* d_out, int out_size, void* d_ws, size_t ws_size,
                              hipStream_t stream) {
  const int*   y_true = (const int*)d_in[0];
  const float* y_pred = (const float*)d_in[1];
  const int*   ilen   = (const int*)d_in[2];
  const int*   llen   = (const int*)d_in[3];
  float*       outp   = (float*)d_out;
  const int    B      = out_size;   // 512
  hipLaunchKernelGGL(ctc_fwd, dim3(B), dim3(64), 0, stream,
                     y_true, y_pred, ilen, llen, outp);
}